// Round 2
// 675.119 us; speedup vs baseline: 1.0120x; 1.0120x over previous
//
#include <hip/hip_runtime.h>
#include <hip/hip_bf16.h>
#include <math.h>

#define N_NODES 100000
#define N_EDGES 1600000
#define NFEAT 512
#define NHID 128
#define NCLASS 40
#define GEMM1_BLOCKS ((N_NODES + 63) / 64)       // 1563: 4 waves x 16 rows
#define COUNT_BLOCKS ((N_EDGES + 1023) / 1024)   // 1563: 256 thr x 4 edges
#define CPAD 1                                   // packed: 400KB LLC-resident histogram
                                                 // (CPAD=16 made every atomic a 64B-line
                                                 //  HBM RMW: 1.6M x 32B fetch + 32B write
                                                 //  = ~100MB scatter traffic, measured)

typedef __attribute__((ext_vector_type(8))) short short8;
typedef __attribute__((ext_vector_type(4))) float floatx4;

__device__ __forceinline__ short f2bf(float f) {
    union { float f; unsigned u; } v; v.f = f;
    unsigned r = v.u + 0x7FFFu + ((v.u >> 16) & 1u);
    return (short)(r >> 16);
}
__device__ __forceinline__ float bf2f(unsigned short u) {
    union { unsigned u; float f; } v; v.u = ((unsigned)u) << 16;
    return v.f;
}
__device__ __forceinline__ unsigned pk2bf(float a, float b) {
    __hip_bfloat162 t = __float22bfloat162_rn(make_float2(a, b));
    union { __hip_bfloat162 h; unsigned u; } v; v.h = t;
    return v.u;
}

// ============================ W1 transpose+convert: W1T[n][k] bf16 ============
__global__ void convert_W1_kernel(const float* __restrict__ W1, unsigned short* __restrict__ W1T) {
    int i = blockIdx.x * 256 + threadIdx.x;       // 65536 total
    int k = i >> 7, n = i & 127;                  // W1 is [512][128]
    W1T[(size_t)n * NFEAT + k] = (unsigned short)f2bf(W1[i]);
}

// ====== Fused: GEMM1 (support1 = bf16(x @ W1)) + edge count w/ rank capture ==
// gemm blocks: 4 waves, each 16 rows x 128 cols (1x8 grid of 16x16x32 MFMA).
// count blocks: 4 edges/thread, atomicAdd to packed counters, save rank.
__global__ __launch_bounds__(256)
void fusedA_kernel(const float* __restrict__ x, const unsigned short* __restrict__ W1T,
                   unsigned short* __restrict__ out,
                   const int* __restrict__ adj_row, int* __restrict__ countsPad,
                   unsigned short* __restrict__ ranks) {
    if (blockIdx.x >= GEMM1_BLOCKS) {
        int base = (blockIdx.x - GEMM1_BLOCKS) * 1024 + threadIdx.x;
        int e0 = base, e1 = base + 256, e2 = base + 512, e3 = base + 768;
        int r0 = (e0 < N_EDGES) ? adj_row[e0] : -1;
        int r1 = (e1 < N_EDGES) ? adj_row[e1] : -1;
        int r2 = (e2 < N_EDGES) ? adj_row[e2] : -1;
        int r3 = (e3 < N_EDGES) ? adj_row[e3] : -1;
        if (r0 >= 0) ranks[e0] = (unsigned short)atomicAdd(&countsPad[(size_t)r0 * CPAD], 1);
        if (r1 >= 0) ranks[e1] = (unsigned short)atomicAdd(&countsPad[(size_t)r1 * CPAD], 1);
        if (r2 >= 0) ranks[e2] = (unsigned short)atomicAdd(&countsPad[(size_t)r2 * CPAD], 1);
        if (r3 >= 0) ranks[e3] = (unsigned short)atomicAdd(&countsPad[(size_t)r3 * CPAD], 1);
        return;
    }
    int t = threadIdx.x;
    int w = t >> 6, l = t & 63;
    int lane16 = l & 15, quad = l >> 4;
    int rowBase = blockIdx.x * 64 + w * 16;

    floatx4 acc[8];
    #pragma unroll
    for (int j = 0; j < 8; j++) acc[j] = (floatx4){0.f, 0.f, 0.f, 0.f};

    int gr = rowBase + lane16;
    if (gr >= N_NODES) gr = N_NODES - 1;          // safe clamp (stores guarded)
    const float* aRow = x + (size_t)gr * NFEAT + quad * 8;

    #pragma unroll 2
    for (int kc = 0; kc < NFEAT; kc += 32) {
        float4 v0 = *(const float4*)(aRow + kc);
        float4 v1 = *(const float4*)(aRow + kc + 4);
        union { short8 s; unsigned u[4]; } av;
        av.u[0] = pk2bf(v0.x, v0.y);
        av.u[1] = pk2bf(v0.z, v0.w);
        av.u[2] = pk2bf(v1.x, v1.y);
        av.u[3] = pk2bf(v1.z, v1.w);
        short8 afr = av.s;
        #pragma unroll
        for (int nt = 0; nt < 8; nt++) {
            const unsigned short* bp =
                W1T + (size_t)(nt * 16 + lane16) * NFEAT + kc + quad * 8;
            short8 bfr = *(const short8*)bp;
            acc[nt] = __builtin_amdgcn_mfma_f32_16x16x32_bf16(afr, bfr, acc[nt], 0, 0, 0);
        }
    }
    // C/D layout: col = lane&15, row = quad*4 + reg
    #pragma unroll
    for (int r = 0; r < 4; r++) {
        int gr2 = rowBase + quad * 4 + r;
        if (gr2 < N_NODES) {
            #pragma unroll
            for (int nt = 0; nt < 8; nt++)
                out[(size_t)gr2 * NHID + nt * 16 + lane16] =
                    (unsigned short)f2bf(acc[nt][r]);
        }
    }
}

// ============================ scans (exclusive prefix over counts) ============
__global__ void scan1_kernel(const int* __restrict__ countsPad, int* __restrict__ offsets,
                             int* __restrict__ blockSums, int n) {
    __shared__ int sdata[256];
    int t = threadIdx.x;
    int base = blockIdx.x * 1024 + t * 4;
    int v0 = (base + 0 < n) ? countsPad[(size_t)(base + 0) * CPAD] : 0;
    int v1 = (base + 1 < n) ? countsPad[(size_t)(base + 1) * CPAD] : 0;
    int v2 = (base + 2 < n) ? countsPad[(size_t)(base + 2) * CPAD] : 0;
    int v3 = (base + 3 < n) ? countsPad[(size_t)(base + 3) * CPAD] : 0;
    int tot = v0 + v1 + v2 + v3;
    sdata[t] = tot;
    __syncthreads();
    for (int ofs = 1; ofs < 256; ofs <<= 1) {
        int w = (t >= ofs) ? sdata[t - ofs] : 0;
        __syncthreads();
        sdata[t] += w;
        __syncthreads();
    }
    int excl = sdata[t] - tot;
    if (base + 0 < n) offsets[base + 0] = excl;
    if (base + 1 < n) offsets[base + 1] = excl + v0;
    if (base + 2 < n) offsets[base + 2] = excl + v0 + v1;
    if (base + 3 < n) offsets[base + 3] = excl + v0 + v1 + v2;
    if (t == 255) blockSums[blockIdx.x] = sdata[255];
}

__global__ void scan2_kernel(int* __restrict__ blockSums, int nb) {
    __shared__ int sdata[128];
    int t = threadIdx.x;
    int v = (t < nb) ? blockSums[t] : 0;
    sdata[t] = v;
    __syncthreads();
    for (int ofs = 1; ofs < 128; ofs <<= 1) {
        int w = (t >= ofs) ? sdata[t - ofs] : 0;
        __syncthreads();
        sdata[t] += w;
        __syncthreads();
    }
    if (t < nb) blockSums[t] = sdata[t] - v;
}

__global__ void scan3_kernel(int* __restrict__ offsets, const int* __restrict__ blockSums,
                             int n, int total) {
    int t = threadIdx.x;
    int base = blockIdx.x * 1024 + t * 4;
    int add = blockSums[blockIdx.x];
    #pragma unroll
    for (int j = 0; j < 4; j++)
        if (base + j < n) offsets[base + j] += add;
    if (blockIdx.x == 0 && t == 0) offsets[n] = total;
}

// ================= fill: NO atomics — position = offset[row] + rank =========
__global__ __launch_bounds__(256)
void fill_kernel(const int* __restrict__ row, const int* __restrict__ col,
                 const float* __restrict__ val, const int* __restrict__ offsets,
                 const unsigned short* __restrict__ ranks, int2* __restrict__ csr) {
    int base = blockIdx.x * 1024 + threadIdx.x;
    #pragma unroll
    for (int i = 0; i < 4; i++) {
        int e = base + i * 256;
        if (e < N_EDGES) {
            int r = row[e];
            int p = offsets[r] + (int)ranks[e];
            csr[p] = make_int2(col[e], __float_as_int(val[e]));
        }
    }
}

// ============================ SpMM1 + bias + ReLU =============================
__global__ __launch_bounds__(256)
void spmm1_kernel(const int* __restrict__ offsets, const int2* __restrict__ csr,
                  const unsigned short* __restrict__ dense, const float* __restrict__ b1,
                  unsigned short* __restrict__ h) {
    int r = blockIdx.x * 4 + (threadIdx.x >> 6);
    int l = threadIdx.x & 63;
    int beg = offsets[r], end = offsets[r + 1];
    float acc0 = 0.f, acc1 = 0.f;
    for (int c0 = beg; c0 < end; c0 += 64) {
        int cnt = min(64, end - c0);
        int2 pk = (l < cnt) ? csr[c0 + l] : make_int2(0, 0);
        int j = 0;
        for (; j + 8 <= cnt; j += 8) {
            unsigned d[8];
            float v[8];
            #pragma unroll
            for (int q = 0; q < 8; q++) {
                int c = __shfl(pk.x, j + q);
                v[q] = __int_as_float(__shfl(pk.y, j + q));
                d[q] = *(const unsigned*)&dense[(size_t)c * NHID + l * 2];
            }
            #pragma unroll
            for (int q = 0; q < 8; q++) {
                acc0 += v[q] * bf2f((unsigned short)d[q]);
                acc1 += v[q] * bf2f((unsigned short)(d[q] >> 16));
            }
        }
        for (; j < cnt; j++) {
            int c = __shfl(pk.x, j);
            float v = __int_as_float(__shfl(pk.y, j));
            unsigned d = *(const unsigned*)&dense[(size_t)c * NHID + l * 2];
            acc0 += v * bf2f((unsigned short)d);
            acc1 += v * bf2f((unsigned short)(d >> 16));
        }
    }
    float r0 = fmaxf(acc0 + b1[l * 2 + 0], 0.f);
    float r1 = fmaxf(acc1 + b1[l * 2 + 1], 0.f);
    *(unsigned*)&h[(size_t)r * NHID + l * 2] = pk2bf(r0, r1);
}

// ================= GEMM2: support2 = bf16(h @ W2), 32 rows/block =============
__global__ __launch_bounds__(256)
void gemm2_kernel(const unsigned short* __restrict__ h, const float* __restrict__ W2,
                  unsigned short* __restrict__ out) {
    __shared__ float W2s[NHID * NCLASS];   // 5120 floats, 20 KB
    __shared__ float hs[32][NHID];         // 16 KB
    int t = threadIdx.x;
    for (int i = t; i < NHID * NCLASS; i += 256) W2s[i] = W2[i];   // 20 strides
    int row0 = blockIdx.x * 32;
    {   // 32 rows x 64 unsigned = 2048 unsigned; 8 per thread
        const unsigned* hsrc = (const unsigned*)(h + (size_t)row0 * NHID);
        #pragma unroll
        for (int j = 0; j < 8; j++) {
            int f = t * 8 + j;          // unsigned index; row = f>>6, c2 = f&63
            unsigned d = hsrc[f];
            hs[f >> 6][(f & 63) * 2 + 0] = bf2f((unsigned short)d);
            hs[f >> 6][(f & 63) * 2 + 1] = bf2f((unsigned short)(d >> 16));
        }
    }
    __syncthreads();
    int w = t >> 6, l = t & 63;
    if (l < NCLASS) {
        float acc[8];
        #pragma unroll
        for (int j = 0; j < 8; j++) acc[j] = 0.f;
        #pragma unroll 4
        for (int k = 0; k < NHID; k++) {
            float wk = W2s[k * NCLASS + l];
            #pragma unroll
            for (int j = 0; j < 8; j++) acc[j] += hs[w * 8 + j][k] * wk;
        }
        #pragma unroll
        for (int j = 0; j < 8; j++)
            out[(size_t)(row0 + w * 8 + j) * NCLASS + l] = (unsigned short)f2bf(acc[j]);
    }
}

// ============================ SpMM2 + bias + log_softmax ======================
__global__ __launch_bounds__(256)
void spmm2_kernel(const int* __restrict__ offsets, const int2* __restrict__ csr,
                  const unsigned short* __restrict__ dense, const float* __restrict__ b2,
                  float* __restrict__ out) {
    int r = blockIdx.x * 4 + (threadIdx.x >> 6);
    int l = threadIdx.x & 63;
    int beg = offsets[r], end = offsets[r + 1];
    float acc = 0.f;
    for (int c0 = beg; c0 < end; c0 += 64) {
        int cnt = min(64, end - c0);
        int2 pk = (l < cnt) ? csr[c0 + l] : make_int2(0, 0);
        int j = 0;
        for (; j + 8 <= cnt; j += 8) {
            float v[8], f[8];
            #pragma unroll
            for (int q = 0; q < 8; q++) {
                int c = __shfl(pk.x, j + q);
                v[q] = __int_as_float(__shfl(pk.y, j + q));
                f[q] = (l < NCLASS) ? bf2f(dense[(size_t)c * NCLASS + l]) : 0.f;
            }
            #pragma unroll
            for (int q = 0; q < 8; q++) acc += v[q] * f[q];
        }
        for (; j < cnt; j++) {
            int c = __shfl(pk.x, j);
            float v = __int_as_float(__shfl(pk.y, j));
            if (l < NCLASS) acc += v * bf2f(dense[(size_t)c * NCLASS + l]);
        }
    }
    float logit = (l < NCLASS) ? (acc + b2[l]) : -INFINITY;
    float m = logit;
    #pragma unroll
    for (int o = 32; o >= 1; o >>= 1) m = fmaxf(m, __shfl_xor(m, o, 64));
    float e = (l < NCLASS) ? __expf(logit - m) : 0.f;
    float s = e;
    #pragma unroll
    for (int o = 32; o >= 1; o >>= 1) s += __shfl_xor(s, o, 64);
    if (l < NCLASS) out[(size_t)r * NCLASS + l] = logit - m - __logf(s);
}

// ============================ launch ============================

extern "C" void kernel_launch(void* const* d_in, const int* in_sizes, int n_in,
                              void* d_out, int out_size, void* d_ws, size_t ws_size,
                              hipStream_t stream) {
    const float* x       = (const float*)d_in[0];
    const int*   adj_row = (const int*)d_in[1];
    const int*   adj_col = (const int*)d_in[2];
    const float* adj_val = (const float*)d_in[3];
    const float* W1      = (const float*)d_in[4];
    const float* b1      = (const float*)d_in[5];
    const float* W2      = (const float*)d_in[6];
    const float* b2      = (const float*)d_in[7];
    float* out = (float*)d_out;

    char* ws = (char*)d_ws;
    size_t off = 0;
    auto alloc = [&](size_t bytes) -> void* {
        void* p = ws + off;
        off += bytes;
        off = (off + 255) & ~(size_t)255;
        return p;
    };
    unsigned short* support1 = (unsigned short*)alloc((size_t)N_NODES * NHID * 2);   // 25.6 MB
    unsigned short* h        = (unsigned short*)alloc((size_t)N_NODES * NHID * 2);   // 25.6 MB
    unsigned short* support2 = (unsigned short*)alloc((size_t)N_NODES * NCLASS * 2); // 8 MB
    unsigned short* W1T      = (unsigned short*)alloc((size_t)NFEAT * NHID * 2);     // 128 KB
    int*   offsets   = (int*)alloc((size_t)(N_NODES + 4) * 4);
    int*   countsPad = (int*)alloc((size_t)N_NODES * CPAD * 4);                      // 400 KB
    int*   blockSums = (int*)alloc(1024 * 4);
    unsigned short* ranks = (unsigned short*)alloc((size_t)N_EDGES * 2);             // 3.2 MB
    int2*  csr       = (int2*)alloc((size_t)N_EDGES * 8);                            // 12.8 MB

    hipMemsetAsync(countsPad, 0, (size_t)N_NODES * CPAD * sizeof(int), stream);
    convert_W1_kernel<<<(NFEAT * NHID) / 256, 256, 0, stream>>>(W1, W1T);
    // fused GEMM1 + edge-count/rank
    fusedA_kernel<<<GEMM1_BLOCKS + COUNT_BLOCKS, 256, 0, stream>>>(
        x, W1T, support1, adj_row, countsPad, ranks);
    int nblk = (N_NODES + 1023) / 1024;   // 98
    scan1_kernel<<<nblk, 256, 0, stream>>>(countsPad, offsets, blockSums, N_NODES);
    scan2_kernel<<<1, 128, 0, stream>>>(blockSums, nblk);
    scan3_kernel<<<nblk, 256, 0, stream>>>(offsets, blockSums, N_NODES, N_EDGES);
    fill_kernel<<<COUNT_BLOCKS, 256, 0, stream>>>(adj_row, adj_col, adj_val,
                                                  offsets, ranks, csr);
    spmm1_kernel<<<N_NODES / 4, 256, 0, stream>>>(offsets, csr, support1, b1, h);
    gemm2_kernel<<<N_NODES / 32, 256, 0, stream>>>(h, W2, support2);
    spmm2_kernel<<<N_NODES / 4, 256, 0, stream>>>(offsets, csr, support2, b2, out);
}